// Round 5
// baseline (303.915 us; speedup 1.0000x reference)
//
#include <hip/hip_runtime.h>
#include <hip/hip_bf16.h>

typedef __hip_bfloat16 bf16;
typedef short bf16x8_t __attribute__((ext_vector_type(8)));  // 8 bf16 = 4 VGPRs
typedef float f32x4_t __attribute__((ext_vector_type(4)));

#define NTOK 8192
#define INF  1024
#define OUTF 1024
#define GS   8
#define KTOT (INF + INF * GS)  // 9216

union b8u { bf16 h[8]; bf16x8_t v; };
union b4u { bf16 h[4]; ushort2 v2[2]; };

// ---------------- prep: B only (A is fused into the GEMM) --------------------------
// B[o,k] = bf16[ bw | sw*ss ], verbatim validated prep_b body.
#define PB ((OUTF * INF * 2) / 256)   // 8192 blocks

__global__ __launch_bounds__(256) void prep_b(const float* __restrict__ bw,
                                              const float* __restrict__ sw,
                                              const float* __restrict__ ss,
                                              bf16* __restrict__ B) {
  const int tid = blockIdx.x * 256 + threadIdx.x;  // 0 .. OUTF*INF*2-1
  const int o = tid >> 11;
  const int r = tid & 2047;
  const float4 w4 = ((const float4*)sw)[tid];
  const float sc = ss[tid >> 1];
  b4u r4;
  r4.h[0] = __float2bfloat16(w4.x * sc);
  r4.h[1] = __float2bfloat16(w4.y * sc);
  r4.h[2] = __float2bfloat16(w4.z * sc);
  r4.h[3] = __float2bfloat16(w4.w * sc);
  const size_t rowb = (size_t)o * KTOT;
  *(ushort2*)(B + rowb + INF + (size_t)r * 4)     = r4.v2[0];
  *(ushort2*)(B + rowb + INF + (size_t)r * 4 + 2) = r4.v2[1];
  if ((tid & 1) == 0)
    B[rowb + (r >> 1)] = __float2bfloat16(bw[tid >> 1]);
}

// ---------------- fused GEMM: C = A(x)[M,K] * B[N,K]^T -----------------------------
// (identical to R4 submission; R4 bench was an infra failure, re-running for data)
// BM=64 BN=512 BK=64, 512 thr = 8 waves (1M x 8N), per-wave 64x64 (verified fragment
// logic verbatim). Grid 2x128 = 256 blocks = 1/CU; XCD j owns br [16j,16j+16) x both bc.
// A (64x64 tile, 8 KB) is PRODUCED per K-tile: thread t owns ONE bf16x8 chunk:
//   row = t>>3, slot c = t&7, content k-chunk kc = c ^ (row&7)  (verified swizzle,
//   carried in CONTENT; ds_write_b128 at byte t*16 = contiguous 1KB/wave).
//   spline chunk = 8 g-values of i = (kt-16)*8 + kc (min-form, R2-validated);
//   base chunk = silu(x[k=kt*64+kc*8 .. +7]).  x prefetched DISTANCE-2 to regs.
// B staged distance-1 via global_load_lds (8x8KB per tile), double-buffered.
// Fragment pipeline: both k-slice frag groups issue at iter top; lgkmcnt(8) before
// MFMA cluster 0 (slice-1 reads + produce drain under it); lgkmcnt(0) before cluster 1.
// Sync ledger (1 barrier/iter):
//   - stages(kt+1)->B[nxt]: B[nxt] last read iter kt-1; those reads lgkm-retired
//     before kt-1's cluster-1, which precedes kt-1's boundary barrier. SAFE.
//   - produce(kt+1)->A[nxt]: same argument. Cross-wave visibility of A[nxt]/B[nxt]
//     for iter kt+1's readers: each wave's ds_write lgkm-retired + own stages
//     vmcnt-retired before boundary barrier. SAFE.
//   - boundary vmcnt(n_x): newest outstanding = x(kt+2) loads (2 dwordx4 base /
//     1 dword spline / 0 tail), everything older (stages kt+1) retired.
#define BM 64
#define BN 512
#define BK 64
#define NT (KTOT / BK)            // 144
#define NBASE (INF / BK)          // 16
#define SA_SZ (BM * BK * 2)       // 8192 B
#define SB_SZ (BN * BK * 2)       // 65536 B
// LDS: A0@0, A1@8192, B0@16384, B1@81920 -> 147456 B total

__global__ __launch_bounds__(512) void gemm_fused(const float* __restrict__ x,
                                                  const bf16* __restrict__ Bm,
                                                  float* __restrict__ C) {
  __shared__ __align__(16) char smem[2 * SA_SZ + 2 * SB_SZ];   // 144 KB
  const int t = threadIdx.x;
  const int lane = t & 63;
  const int w = t >> 6;            // wave 0..7
  const int wn = w * 64;           // wave column quadrant (wm = 0: BM=64)
  // XCD-aware remap: lid = by*2+bx; xcd = lid&7 owns br [16*xcd, 16*xcd+16), both bc.
  const int lid = blockIdx.y * gridDim.x + blockIdx.x;
  const int xcd = lid & 7;
  const int idx = lid >> 3;                        // 0..31
  const int br = xcd * 16 + (idx >> 1);            // M tile (0..127)
  const int bc = idx & 1;                          // N tile (0..1)

  // ---- B staging mapping (verified machinery) ----
  const int srow = t >> 3;                         // 0..63 (+64d per loadset)
  const int scol = ((t & 7) ^ (srow & 7)) * 8;     // swizzled source k-offset (elems)
  const bf16* gB = Bm + (size_t)(bc * BN + srow) * KTOT + scol;
  const int wb = w * 1024;

  // ---- A produce mapping ----
  const int arow = t >> 3;                         // 0..63
  const int akc = (t & 7) ^ (arow & 7);            // k-chunk this thread computes
  const float* xrow = x + (size_t)(br * BM + arow) * INF;

  const float EG[8]  = {0.36787944f, 0.47236655f, 0.60653066f, 0.77880078f,
                        1.0f, 1.28402542f, 1.64872127f, 2.11700002f};   // e^{g_v}
  const float EIG[8] = {2.71828183f, 2.11700002f, 1.64872127f, 1.28402542f,
                        1.0f, 0.77880078f, 0.60653066f, 0.47236655f};   // e^{-g_v}

  // ---- fragment addressing (verified, verbatim) ----
  const int frow = lane & 15;
  const int fk = (lane >> 4) * 8;
  const int fsw = frow & 7;
  const int swk0 = (((0  + fk) >> 3) ^ fsw) * 8;
  const int swk1 = (((32 + fk) >> 3) ^ fsw) * 8;

  f32x4_t acc[4][4] = {};
  float xe[8], xo[8];   // x prefetch regs, parity-named (rule #20: no runtime index)

#define BSTAGE(nxt_, kt_) do { \
    _Pragma("unroll") \
    for (int d = 0; d < 8; ++d) \
      __builtin_amdgcn_global_load_lds( \
        (const __attribute__((address_space(1))) void*)(gB + (size_t)d * 64 * KTOT + (size_t)(kt_) * BK), \
        (__attribute__((address_space(3))) void*)(smem + 2 * SA_SZ + (nxt_) * SB_SZ + d * 8192 + wb), 16, 0, 0); \
  } while (0)

#define XLOAD(dst_, ktp_) do { \
    if ((ktp_) < NBASE) { \
      const float* xp_ = xrow + (ktp_) * BK + akc * 8; \
      const float4 a_ = ((const float4*)xp_)[0]; \
      const float4 b_ = ((const float4*)xp_)[1]; \
      dst_[0]=a_.x; dst_[1]=a_.y; dst_[2]=a_.z; dst_[3]=a_.w; \
      dst_[4]=b_.x; dst_[5]=b_.y; dst_[6]=b_.z; dst_[7]=b_.w; \
    } else { \
      dst_[0] = xrow[((ktp_) - NBASE) * 8 + akc]; \
    } \
  } while (0)

#define PRODUCE(nxt_, ktp_, src_) do { \
    b8u pk_; \
    if ((ktp_) < NBASE) { \
      _Pragma("unroll") \
      for (int j = 0; j < 8; ++j) { \
        const float v_ = src_[j]; \
        pk_.h[j] = __float2bfloat16(v_ / (1.0f + __expf(-v_))); \
      } \
    } else { \
      const float xv_ = src_[0]; \
      const float en_ = __expf(-xv_); \
      const float ep_ = __expf(xv_); \
      _Pragma("unroll") \
      for (int g = 0; g < 8; ++g) \
        pk_.h[g] = __float2bfloat16(fminf(en_ * EG[g], ep_ * EIG[g])); \
    } \
    *(bf16x8_t*)(smem + (nxt_) * SA_SZ + t * 16) = pk_.v; \
  } while (0)

#define BODY(KT_, CUR_, NXT_, XLD_, XPR_) do {                                     \
    const bool pf1_ = (KT_) + 1 < NT;                                              \
    if (pf1_) BSTAGE(NXT_, (KT_) + 1);                                             \
    if ((KT_) + 2 < NT) XLOAD(XLD_, (KT_) + 2);                                    \
    const bf16* sAc_ = (const bf16*)(smem + (CUR_) * SA_SZ);                       \
    const bf16* sBc_ = (const bf16*)(smem + 2 * SA_SZ + (CUR_) * SB_SZ);           \
    bf16x8_t a0_[4], b0_[4], a1_[4], b1_[4];                                       \
    _Pragma("unroll")                                                              \
    for (int i = 0; i < 4; ++i) {                                                  \
      a0_[i] = *(const bf16x8_t*)(sAc_ + (i * 16 + frow) * BK + swk0);             \
      b0_[i] = *(const bf16x8_t*)(sBc_ + (wn + i * 16 + frow) * BK + swk0);        \
    }                                                                              \
    __builtin_amdgcn_sched_barrier(0);  /* keep group0 reads oldest in lgkm queue */\
    _Pragma("unroll")                                                              \
    for (int i = 0; i < 4; ++i) {                                                  \
      a1_[i] = *(const bf16x8_t*)(sAc_ + (i * 16 + frow) * BK + swk1);             \
      b1_[i] = *(const bf16x8_t*)(sBc_ + (wn + i * 16 + frow) * BK + swk1);        \
    }                                                                              \
    asm volatile("s_waitcnt lgkmcnt(8)" ::: "memory");  /* group0 retired */       \
    __builtin_amdgcn_sched_barrier(0);                                             \
    __builtin_amdgcn_s_setprio(1);                                                 \
    _Pragma("unroll")                                                              \
    for (int i = 0; i < 4; ++i)                                                    \
      _Pragma("unroll")                                                            \
      for (int j = 0; j < 4; ++j)                                                  \
        acc[i][j] = __builtin_amdgcn_mfma_f32_16x16x32_bf16(a0_[i], b0_[j], acc[i][j], 0, 0, 0); \
    __builtin_amdgcn_s_setprio(0);                                                 \
    if (pf1_) PRODUCE(NXT_, (KT_) + 1, XPR_);                                      \
    asm volatile("s_waitcnt lgkmcnt(0)" ::: "memory");  /* group1 + ds_write */    \
    __builtin_amdgcn_sched_barrier(0);                                             \
    __builtin_amdgcn_s_setprio(1);                                                 \
    _Pragma("unroll")                                                              \
    for (int i = 0; i < 4; ++i)                                                    \
      _Pragma("unroll")                                                            \
      for (int j = 0; j < 4; ++j)                                                  \
        acc[i][j] = __builtin_amdgcn_mfma_f32_16x16x32_bf16(a1_[i], b1_[j], acc[i][j], 0, 0, 0); \
    __builtin_amdgcn_s_setprio(0);                                                 \
    if ((KT_) + 2 < NBASE)   { asm volatile("s_waitcnt vmcnt(2)" ::: "memory"); }  \
    else if ((KT_) + 2 < NT) { asm volatile("s_waitcnt vmcnt(1)" ::: "memory"); }  \
    else                     { asm volatile("s_waitcnt vmcnt(0)" ::: "memory"); }  \
    __builtin_amdgcn_s_barrier();                                                  \
  } while (0)

  // ---- prologue: B(0)->buf0, x(0)->xe, x(1)->xo, produce A(0)->buf0 ----
  BSTAGE(0, 0);
  XLOAD(xe, 0);
  XLOAD(xo, 1);
  PRODUCE(0, 0, xe);   // compiler inserts the counted vmcnt for xe before use
  asm volatile("s_waitcnt vmcnt(0) lgkmcnt(0)" ::: "memory");
  __builtin_amdgcn_s_barrier();
  __builtin_amdgcn_sched_barrier(0);

  for (int kt = 0; kt < NT; kt += 2) {   // NT=144 even
    BODY(kt,     0, 1, xe, xo);
    BODY(kt + 1, 1, 0, xo, xe);
  }

  // epilogue: D mapping col = lane&15, row = (lane>>4)*4 + reg  [m89/m91]
  const int ccol = bc * BN + wn + frow;
  const int crow0 = br * BM + (lane >> 4) * 4;
  #pragma unroll
  for (int i = 0; i < 4; ++i)
    #pragma unroll
    for (int r = 0; r < 4; ++r) {
      float* cp = C + (size_t)(crow0 + i * 16 + r) * OUTF + ccol;
      #pragma unroll
      for (int j = 0; j < 4; ++j)
        cp[j * 16] = acc[i][j][r];
    }
#undef BSTAGE
#undef XLOAD
#undef PRODUCE
#undef BODY
}

// ---------------- fallback (ws too small): naive, correctness-only ----------------
__global__ __launch_bounds__(256) void naive_kern(const float* __restrict__ x,
                                                  const float* __restrict__ bw,
                                                  const float* __restrict__ sw,
                                                  const float* __restrict__ ss,
                                                  const float* __restrict__ grid,
                                                  float* __restrict__ out) {
  const int idx = blockIdx.x * 256 + threadIdx.x;  // n*OUTF + o
  const int o = idx & (OUTF - 1);
  const int n = idx >> 10;
  float acc = 0.f;
  for (int i = 0; i < INF; ++i) {
    const float xv = x[n * INF + i];
    const float s = xv / (1.f + __expf(-xv));
    acc += s * bw[o * INF + i];
    const float sc = ss[o * INF + i];
    #pragma unroll
    for (int g = 0; g < 8; ++g) {
      const float gv = grid[i * 8 + g];
      acc += __expf(-fabsf(xv - gv)) * sw[(size_t)(o * INF + i) * 8 + g] * sc;
    }
  }
  out[idx] = acc;
}

extern "C" void kernel_launch(void* const* d_in, const int* in_sizes, int n_in,
                              void* d_out, int out_size, void* d_ws, size_t ws_size,
                              hipStream_t stream) {
  const float* x    = (const float*)d_in[0];
  const float* bw   = (const float*)d_in[1];
  const float* sw   = (const float*)d_in[2];
  const float* ss   = (const float*)d_in[3];
  const float* grid = (const float*)d_in[4];
  float* out = (float*)d_out;

  const size_t needB = (size_t)OUTF * KTOT * sizeof(bf16);  // ~19 MB

  if (ws_size >= needB) {
    bf16* B = (bf16*)d_ws;
    prep_b<<<PB, 256, 0, stream>>>(bw, sw, ss, B);
    dim3 g(2, 128);   // (bc-halves, br) = 256 blocks = 1/CU
    gemm_fused<<<g, 512, 0, stream>>>(x, B, out);
  } else {
    naive_kern<<<(NTOK * OUTF) / 256, 256, 0, stream>>>(x, bw, sw, ss, grid, out);
  }
}

// Round 6
// 282.853 us; speedup vs baseline: 1.0745x; 1.0745x over previous
//
#include <hip/hip_runtime.h>
#include <hip/hip_bf16.h>

typedef __hip_bfloat16 bf16;
typedef short bf16x8_t __attribute__((ext_vector_type(8)));  // 8 bf16 = 4 VGPRs
typedef short s4_t __attribute__((ext_vector_type(4)));      // 4 bf16 = 8B
typedef float f32x4_t __attribute__((ext_vector_type(4)));

#define NTOK 8192
#define INF  1024
#define OUTF 1024
#define GS   8
#define KTOT (INF + INF * GS)  // 9216

union b8u { bf16 h[8]; bf16x8_t v; };
union b4u { bf16 h[4]; ushort2 v2[2]; };
union b4s { bf16 h[4]; s4_t v; };

// ---------------- fused prep (R3 version VERBATIM — measured good) -----------------
// Blocks [0, PA): A[n,k] = bf16[ silu(x) | exp(-|x-g_v|) ], 4 elems/thread, min-form.
// Blocks [PA, PA+PB): B[o,k] = bf16[ bw | sw*ss ].
#define PA ((NTOK * INF / 4) / 256)   // 8192 blocks
#define PB ((OUTF * INF * 2) / 256)   // 8192 blocks

__global__ __launch_bounds__(256) void prep_fused(const float* __restrict__ x,
                                                  const float* __restrict__ bw,
                                                  const float* __restrict__ sw,
                                                  const float* __restrict__ ss,
                                                  bf16* __restrict__ A,
                                                  bf16* __restrict__ B) {
  const int b = blockIdx.x;
  if (b < PA) {
    const float EG[8]  = {0.36787944f, 0.47236655f, 0.60653066f, 0.77880078f,
                          1.0f, 1.28402542f, 1.64872127f, 2.11700002f};   // e^{g_v}
    const float EIG[8] = {2.71828183f, 2.11700002f, 1.64872127f, 1.28402542f,
                          1.0f, 0.77880078f, 0.60653066f, 0.47236655f};   // e^{-g_v}
    const int tid = b * 256 + threadIdx.x;      // 0 .. NTOK*INF/4-1
    const int qi = tid & 255;                   // i-quad within row; i = qi*4+j
    const int n = tid >> 8;
    const float4 x4 = ((const float4*)x)[tid];  // x[n*INF + qi*4 ..+3]
    const float xf[4] = {x4.x, x4.y, x4.z, x4.w};
    b4s sil;
    b8u kn[4];
    #pragma unroll
    for (int j = 0; j < 4; ++j) {
      const float xv = xf[j];
      const float en = __expf(-xv);
      const float ep = __expf(xv);
      sil.h[j] = __float2bfloat16(xv / (1.0f + en));   // SiLU
      #pragma unroll
      for (int g = 0; g < 8; ++g)
        kn[j].h[g] = __float2bfloat16(fminf(en * EG[g], ep * EIG[g]));
    }
    const size_t rowb = (size_t)n * KTOT;
    *(s4_t*)(A + rowb + qi * 4) = sil.v;                       // 8B aligned
    #pragma unroll
    for (int j = 0; j < 4; ++j)                                 // 4x16B contiguous
      *(bf16x8_t*)(A + rowb + INF + (size_t)(qi * 4 + j) * 8) = kn[j].v;
  } else {
    const int tid = (b - PA) * 256 + threadIdx.x;  // 0 .. OUTF*INF*2-1
    const int o = tid >> 11;
    const int r = tid & 2047;
    const float4 w4 = ((const float4*)sw)[tid];
    const float sc = ss[tid >> 1];
    b4u r4;
    r4.h[0] = __float2bfloat16(w4.x * sc);
    r4.h[1] = __float2bfloat16(w4.y * sc);
    r4.h[2] = __float2bfloat16(w4.z * sc);
    r4.h[3] = __float2bfloat16(w4.w * sc);
    const size_t rowb = (size_t)o * KTOT;
    *(ushort2*)(B + rowb + INF + (size_t)r * 4)     = r4.v2[0];
    *(ushort2*)(B + rowb + INF + (size_t)r * 4 + 2) = r4.v2[1];
    if ((tid & 1) == 0)
      B[rowb + (r >> 1)] = __float2bfloat16(bw[tid >> 1]);
  }
}

// ---------------- GEMM: C[M,N] = A[M,K] * B[N,K]^T ---------------------------------
// R3 base (3-ring counted-vmcnt, XCD remap, verified PASS at 159us/973TF) with ONE
// structural change: single-barrier-per-K-tile + counted lgkm split.
//   old: [reads s0 | stage | BAR | lgkm(0) | MFMA0 | BAR] x2  (4 barriers/tile,
//        every cluster waits for a FULL drain -> reads serialize with MFMA)
//   new: stage(6) ; reads s0(8) ; reads s1(8) ; lgkm(8) -> MFMA0 (s1 reads drain
//        under it) ; lgkm(0) -> MFMA1 ; vmcnt(6) ; BAR      (1 barrier/tile)
// Sync ledger:
//   - reads(cur) safe after boundary barrier: tile kt staged 2 iters ago, retired
//     by each wave's vmcnt(6) at end of iter kt-1 (those stages older than the 6
//     then-outstanding), published by that barrier.
//   - stages(pb = tile kt-1's buffer): that buffer's reads lgkm-retired at iter
//     kt-1's lgkm(0) (before cluster1), before its boundary barrier. SAFE.
//   - lgkm(8): this wave issued exactly 16 ds_reads this iter (s0 oldest, pinned
//     by sched_barrier between groups); <=8 outstanding => s0 retired. No other
//     lgkm ops in the loop (no SMEM/flat/ds_write).
//   - tail kt>=NT-2: no stages, boundary vmcnt(0).
#define BM 256
#define BN 128
#define BK 64
#define NT (KTOT / BK)            // 144
#define LDSA (BM * BK * 2)        // 32768 B
#define LDSB (BN * BK * 2)        // 16384 B
#define LDSBUF (LDSA + LDSB)      // 49152 B

__global__ __launch_bounds__(512) void gemm_bt2(const bf16* __restrict__ A,
                                                const bf16* __restrict__ B,
                                                float* __restrict__ C) {
  __shared__ __align__(16) char smem[3 * LDSBUF];   // 144 KB ring
  const int t = threadIdx.x;
  const int lane = t & 63;
  const int w = t >> 6;            // wave 0..7
  const int wm = (w >> 1) * 64;    // 0,64,128,192
  const int wn = (w & 1) * 64;     // 0,64
  // XCD-aware remap (bijective on 0..255): xcd = lid&7 gets br 4*xcd..4*xcd+3, all bc.
  const int lid = blockIdx.y * 8 + blockIdx.x;     // linear id, x fastest
  const int br = (lid & 7) * 4 + ((lid >> 3) & 3); // M tile (0..31)
  const int bc = lid >> 5;                         // N tile (0..7)

  const int srow = t >> 3;                         // 0..63
  const int scol = ((t & 7) ^ (srow & 7)) * 8;     // swizzled source k-offset (elems)
  const bf16* gA = A + (size_t)(br * BM + srow) * KTOT + scol;
  const bf16* gB = B + (size_t)(bc * BN + srow) * KTOT + scol;
  const int wb = w * 1024;                         // wave's 64 lanes x 16B

  // fragment addressing (verified, verbatim)
  const int frow = lane & 15;
  const int fk = (lane >> 4) * 8;
  const int fsw = frow & 7;
  const int swk0 = (((0  + fk) >> 3) ^ fsw) * 8;   // kk=0  swizzled elem offset
  const int swk1 = (((32 + fk) >> 3) ^ fsw) * 8;   // kk=32

  f32x4_t acc[4][4] = {};

#define STAGE_A(b_, i_, kt_) \
  __builtin_amdgcn_global_load_lds( \
      (const __attribute__((address_space(1))) void*)(gA + (size_t)(i_) * 32 * KTOT + (size_t)(kt_) * BK), \
      (__attribute__((address_space(3))) void*)(smem + (b_) * LDSBUF + (i_) * 8192 + wb), 16, 0, 0)
#define STAGE_B(b_, i_, kt_) \
  __builtin_amdgcn_global_load_lds( \
      (const __attribute__((address_space(1))) void*)(gB + (size_t)(i_) * 32 * KTOT + (size_t)(kt_) * BK), \
      (__attribute__((address_space(3))) void*)(smem + (b_) * LDSBUF + LDSA + (i_) * 8192 + wb), 16, 0, 0)
  // NOTE: srow spans 64 rows (512 thr / 8); inst stride is 64 rows => i_*32*KTOT
  // would be wrong -- A insts stride 64 rows: i_ in {0..3} covers 256 rows via
  // (i_*64). Kept as macro args below with explicit *64 factors.
#undef STAGE_A
#undef STAGE_B
#define STAGE_A(b_, i_, kt_) \
  __builtin_amdgcn_global_load_lds( \
      (const __attribute__((address_space(1))) void*)(gA + (size_t)(i_) * 64 * KTOT + (size_t)(kt_) * BK), \
      (__attribute__((address_space(3))) void*)(smem + (b_) * LDSBUF + (i_) * 8192 + wb), 16, 0, 0)
#define STAGE_B(b_, i_, kt_) \
  __builtin_amdgcn_global_load_lds( \
      (const __attribute__((address_space(1))) void*)(gB + (size_t)(i_) * 64 * KTOT + (size_t)(kt_) * BK), \
      (__attribute__((address_space(3))) void*)(smem + (b_) * LDSBUF + LDSA + (i_) * 8192 + wb), 16, 0, 0)

  // prologue: tile 0 -> buf0, tile 1 -> buf1 (12 loads in flight)
  STAGE_A(0, 0, 0); STAGE_A(0, 1, 0); STAGE_A(0, 2, 0); STAGE_A(0, 3, 0);
  STAGE_B(0, 0, 0); STAGE_B(0, 1, 0);
  STAGE_A(1, 0, 1); STAGE_A(1, 1, 1); STAGE_A(1, 2, 1); STAGE_A(1, 3, 1);
  STAGE_B(1, 0, 1); STAGE_B(1, 1, 1);
  asm volatile("s_waitcnt vmcnt(6)" ::: "memory");   // tile 0 resident
  __builtin_amdgcn_s_barrier();

  int cb = 0;
  for (int kt = 0; kt < NT; ++kt) {
    const bf16* sAc = (const bf16*)(smem + cb * LDSBUF);
    const bf16* sBc = (const bf16*)(smem + cb * LDSBUF + LDSA);
    const int pb = (cb == 0) ? 2 : cb - 1;           // (kt+2)%3
    const bool pf = kt < NT - 2;

    // stages for tile kt+2 (earliest issue = max slack; vm-only, no lgkm impact)
    if (pf) {
      STAGE_A(pb, 0, kt + 2); STAGE_A(pb, 1, kt + 2);
      STAGE_A(pb, 2, kt + 2); STAGE_A(pb, 3, kt + 2);
      STAGE_B(pb, 0, kt + 2); STAGE_B(pb, 1, kt + 2);
    }

    bf16x8_t a0[4], b0[4], a1[4], b1[4];
    // ---- read group 0 (slice kk=0): oldest 8 in lgkm queue ----
    #pragma unroll
    for (int i = 0; i < 4; ++i) {
      a0[i] = *(const bf16x8_t*)(sAc + (wm + i * 16 + frow) * BK + swk0);
      b0[i] = *(const bf16x8_t*)(sBc + (wn + i * 16 + frow) * BK + swk0);
    }
    __builtin_amdgcn_sched_barrier(0);   // pin group boundary (lgkm(8) semantics)
    // ---- read group 1 (slice kk=32): newest 8 ----
    #pragma unroll
    for (int i = 0; i < 4; ++i) {
      a1[i] = *(const bf16x8_t*)(sAc + (wm + i * 16 + frow) * BK + swk1);
      b1[i] = *(const bf16x8_t*)(sBc + (wn + i * 16 + frow) * BK + swk1);
    }
    asm volatile("s_waitcnt lgkmcnt(8)" ::: "memory");  // group 0 retired
    __builtin_amdgcn_sched_barrier(0);
    __builtin_amdgcn_s_setprio(1);
    #pragma unroll
    for (int i = 0; i < 4; ++i)
      #pragma unroll
      for (int j = 0; j < 4; ++j)
        acc[i][j] = __builtin_amdgcn_mfma_f32_16x16x32_bf16(a0[i], b0[j], acc[i][j], 0, 0, 0);
    __builtin_amdgcn_s_setprio(0);
    asm volatile("s_waitcnt lgkmcnt(0)" ::: "memory");  // group 1 retired (drained under MFMA0)
    __builtin_amdgcn_sched_barrier(0);
    __builtin_amdgcn_s_setprio(1);
    #pragma unroll
    for (int i = 0; i < 4; ++i)
      #pragma unroll
      for (int j = 0; j < 4; ++j)
        acc[i][j] = __builtin_amdgcn_mfma_f32_16x16x32_bf16(a1[i], b1[j], acc[i][j], 0, 0, 0);
    __builtin_amdgcn_s_setprio(0);
    // boundary: counted wait — tile kt+1's stages are strictly older than the 6
    // issued this iteration; vmcnt(6) retires them without draining the pipe.
    if (pf) { asm volatile("s_waitcnt vmcnt(6)" ::: "memory"); }
    else    { asm volatile("s_waitcnt vmcnt(0)" ::: "memory"); }
    __builtin_amdgcn_s_barrier();

    cb = (cb == 2) ? 0 : cb + 1;
  }

  // epilogue: D mapping col = lane&15, row = (lane>>4)*4 + reg  [m89/m91]
  const int ccol = bc * BN + wn + frow;
  const int crow0 = br * BM + wm + (lane >> 4) * 4;
  #pragma unroll
  for (int i = 0; i < 4; ++i)
    #pragma unroll
    for (int r = 0; r < 4; ++r) {
      float* cp = C + (size_t)(crow0 + i * 16 + r) * OUTF + ccol;
      #pragma unroll
      for (int j = 0; j < 4; ++j)
        cp[j * 16] = acc[i][j][r];
    }
#undef STAGE_A
#undef STAGE_B
}

// ---------------- fallback (ws too small): naive, correctness-only ----------------
__global__ __launch_bounds__(256) void naive_kern(const float* __restrict__ x,
                                                  const float* __restrict__ bw,
                                                  const float* __restrict__ sw,
                                                  const float* __restrict__ ss,
                                                  const float* __restrict__ grid,
                                                  float* __restrict__ out) {
  const int idx = blockIdx.x * 256 + threadIdx.x;  // n*OUTF + o
  const int o = idx & (OUTF - 1);
  const int n = idx >> 10;
  float acc = 0.f;
  for (int i = 0; i < INF; ++i) {
    const float xv = x[n * INF + i];
    const float s = xv / (1.f + __expf(-xv));
    acc += s * bw[o * INF + i];
    const float sc = ss[o * INF + i];
    #pragma unroll
    for (int g = 0; g < 8; ++g) {
      const float gv = grid[i * 8 + g];
      acc += __expf(-fabsf(xv - gv)) * sw[(size_t)(o * INF + i) * 8 + g] * sc;
    }
  }
  out[idx] = acc;
}

extern "C" void kernel_launch(void* const* d_in, const int* in_sizes, int n_in,
                              void* d_out, int out_size, void* d_ws, size_t ws_size,
                              hipStream_t stream) {
  const float* x    = (const float*)d_in[0];
  const float* bw   = (const float*)d_in[1];
  const float* sw   = (const float*)d_in[2];
  const float* ss   = (const float*)d_in[3];
  const float* grid = (const float*)d_in[4];
  float* out = (float*)d_out;

  const size_t needA = (size_t)NTOK * KTOT * sizeof(bf16);  // ~151 MB
  const size_t needB = (size_t)OUTF * KTOT * sizeof(bf16);  // ~19 MB

  if (ws_size >= needA + needB) {
    bf16* A = (bf16*)d_ws;
    bf16* B = (bf16*)((char*)d_ws + needA);
    prep_fused<<<PA + PB, 256, 0, stream>>>(x, bw, sw, ss, A, B);
    dim3 g(OUTF / BN, NTOK / BM);  // (8, 32) = 256 blocks = 1/CU
    gemm_bt2<<<g, 512, 0, stream>>>(A, B, out);
  } else {
    naive_kern<<<(NTOK * OUTF) / 256, 256, 0, stream>>>(x, bw, sw, ss, grid, out);
  }
}